// Round 6
// baseline (396.813 us; speedup 1.0000x reference)
//
#include <hip/hip_runtime.h>

// QLSTM: SEQ=512, BATCH=512, IN_DIM=128, NQ=8, D=136, gates (f,i,g,o)
// out = (512,512,8) ++ h_f(512,8) ++ c_f(512,8), f32.
// K1: ZX[m][gq] = X[m][:128] . W[gq][:128] + b[gq] + qp[gq]   (parallel)
// K2: sequential scan; cross-lane ONLY via __builtin_amdgcn_update_dpp.
//     Activations on [-1,1] args via polynomials (no exp/rcp on that path).

#define SEQ_LEN 512
#define BATCH_N 512
#define IN_DIMC 128
#define DTOT 136
#define OUT_MAIN (SEQ_LEN * BATCH_N * 8)

// ---------------------------------------------------------------------------
// Kernel 1: 256 thr/block, 4 rows/thread, W staged [k][gq] in LDS (broadcast).
// unroll 1 on k-loop prevents load-hoist VGPR spill. Bias folded in epilogue.
// ---------------------------------------------------------------------------
__global__ __launch_bounds__(256, 1) void zx_gemm(
    const float* __restrict__ X, const float* __restrict__ W,
    const float* __restrict__ bv, const float* __restrict__ qp,
    float* __restrict__ ZX)
{
    __shared__ __align__(16) float Wl[IN_DIMC * 32];   // [k][gq]
    const int tid = threadIdx.x;
    #pragma unroll
    for (int i = 0; i < 16; ++i) {
        int idx = i * 256 + tid;
        Wl[idx] = W[(idx & 31) * DTOT + (idx >> 5)];
    }
    __syncthreads();

    const long r0 = (long)blockIdx.x * 1024 + tid;
    const long r1 = r0 + 256, r2 = r0 + 512, r3 = r0 + 768;
    const float4* __restrict__ X0 = (const float4*)X + r0 * 32;
    const float4* __restrict__ X1 = (const float4*)X + r1 * 32;
    const float4* __restrict__ X2 = (const float4*)X + r2 * 32;
    const float4* __restrict__ X3 = (const float4*)X + r3 * 32;
    const float4* __restrict__ W4 = (const float4*)Wl;

    float4 a0[8], a1[8], a2[8], a3[8];
    #pragma unroll
    for (int qq = 0; qq < 8; ++qq) {
        a0[qq] = make_float4(0.f, 0.f, 0.f, 0.f);
        a1[qq] = make_float4(0.f, 0.f, 0.f, 0.f);
        a2[qq] = make_float4(0.f, 0.f, 0.f, 0.f);
        a3[qq] = make_float4(0.f, 0.f, 0.f, 0.f);
    }

    float4 xa = X0[0], xb = X1[0], xc = X2[0], xd = X3[0];
    #pragma unroll 1
    for (int k4 = 0; k4 < 32; ++k4) {
        float4 xan = xa, xbn = xb, xcn = xc, xdn = xd;
        if (k4 < 31) {
            xan = X0[k4 + 1]; xbn = X1[k4 + 1];
            xcn = X2[k4 + 1]; xdn = X3[k4 + 1];
        }
        #pragma unroll
        for (int c = 0; c < 4; ++c) {
            const float va = (c==0)?xa.x:(c==1)?xa.y:(c==2)?xa.z:xa.w;
            const float vb = (c==0)?xb.x:(c==1)?xb.y:(c==2)?xb.z:xb.w;
            const float vc = (c==0)?xc.x:(c==1)?xc.y:(c==2)?xc.z:xc.w;
            const float vd = (c==0)?xd.x:(c==1)?xd.y:(c==2)?xd.z:xd.w;
            #pragma unroll
            for (int qq = 0; qq < 8; ++qq) {
                const float4 w = W4[(k4 * 4 + c) * 8 + qq];
                a0[qq].x = fmaf(va, w.x, a0[qq].x);
                a0[qq].y = fmaf(va, w.y, a0[qq].y);
                a0[qq].z = fmaf(va, w.z, a0[qq].z);
                a0[qq].w = fmaf(va, w.w, a0[qq].w);
                a1[qq].x = fmaf(vb, w.x, a1[qq].x);
                a1[qq].y = fmaf(vb, w.y, a1[qq].y);
                a1[qq].z = fmaf(vb, w.z, a1[qq].z);
                a1[qq].w = fmaf(vb, w.w, a1[qq].w);
                a2[qq].x = fmaf(vc, w.x, a2[qq].x);
                a2[qq].y = fmaf(vc, w.y, a2[qq].y);
                a2[qq].z = fmaf(vc, w.z, a2[qq].z);
                a2[qq].w = fmaf(vc, w.w, a2[qq].w);
                a3[qq].x = fmaf(vd, w.x, a3[qq].x);
                a3[qq].y = fmaf(vd, w.y, a3[qq].y);
                a3[qq].z = fmaf(vd, w.z, a3[qq].z);
                a3[qq].w = fmaf(vd, w.w, a3[qq].w);
            }
        }
        xa = xan; xb = xbn; xc = xcn; xd = xdn;
    }

    float4* __restrict__ Z4 = (float4*)ZX;
    #pragma unroll
    for (int qq = 0; qq < 8; ++qq) {
        const int g0 = qq * 4;
        const float b0 = bv[g0+0] + qp[g0+0];
        const float b1_ = bv[g0+1] + qp[g0+1];
        const float b2 = bv[g0+2] + qp[g0+2];
        const float b3 = bv[g0+3] + qp[g0+3];
        float4 o0 = a0[qq], o1 = a1[qq], o2 = a2[qq], o3 = a3[qq];
        o0.x += b0; o0.y += b1_; o0.z += b2; o0.w += b3;
        o1.x += b0; o1.y += b1_; o1.z += b2; o1.w += b3;
        o2.x += b0; o2.y += b1_; o2.z += b2; o2.w += b3;
        o3.x += b0; o3.y += b1_; o3.z += b2; o3.w += b3;
        Z4[r0 * 8 + qq] = o0;
        Z4[r1 * 8 + qq] = o1;
        Z4[r2 * 8 + qq] = o2;
        Z4[r3 * 8 + qq] = o3;
    }
}

// ---------------------------------------------------------------------------
// Kernel 2: 16 lanes per batch row (4 rows/wave). Lane l16 = l&15, q = l&7.
// hB = l16>>3: hB=0 owns gates {0:f, 2:g~(tanh)}, hB=1 owns {1:i, 3:o}.
// Cross-lane: DPP only (jmap-calibrated ror; direction-calibrated shr/shl;
// self-inverse ror:8 partner exchange).
// ---------------------------------------------------------------------------
#define DPP_F(x, ctrl) \
    __builtin_bit_cast(float, __builtin_amdgcn_update_dpp( \
        0, __builtin_bit_cast(int, (x)), (ctrl), 0xF, 0xF, true))

// sigmoid on [-1,1]: 0.5 + x*(A0 + x^2*(A1 + x^2*A2)), err <= 2e-4
#define SIG_A0 0.25f
#define SIG_A1 (-0.020833333f)
#define SIG_A2 0.0020833333f
// tanh on [-1,1]: x*(T0 + y*(T1 + y*(T2 + y*T3))), y=x^2, err <= ~1e-4
#define TNH_T0 0.999752f
#define TNH_T1 (-0.329199f)
#define TNH_T2 0.115682f
#define TNH_T3 (-0.024641f)
#define NL2E2 (-2.8853900817779268f)   // -2*log2(e)

__global__ __launch_bounds__(64) void qlstm_scan(
    const float* __restrict__ ZX, const float* __restrict__ W,
    const float* __restrict__ h0, const float* __restrict__ c0,
    float* __restrict__ out)
{
    const int l   = threadIdx.x;       // 0..63
    const int l16 = l & 15;
    const int q   = l & 7;
    const int hB  = l16 >> 3;
    const int row = blockIdx.x * 4 + (l >> 4);
    const int gq0 = l16;               // gate hB   (f or i), qubit q
    const int gq1 = 16 + l16;          // gate 2+hB (g~ or o), qubit q

    // --- calibrate row_ror index map: jmap[r] = q-index received under ror r
    const float qf = (float)q;
    int jmap[8];
    jmap[0] = q;
    jmap[1] = (int)DPP_F(qf, 0x121);
    jmap[2] = (int)DPP_F(qf, 0x122);
    jmap[3] = (int)DPP_F(qf, 0x123);
    jmap[4] = (int)DPP_F(qf, 0x124);
    jmap[5] = (int)DPP_F(qf, 0x125);
    jmap[6] = (int)DPP_F(qf, 0x126);
    jmap[7] = (int)DPP_F(qf, 0x127);

    // --- calibrate shr direction; wave-uniform via lane 1 (q=1) probe
    const int dircal = ((int)DPP_F(qf, 0x111) == q - 1) ? 1 : 0;
    const int dirU = __builtin_amdgcn_readlane(dircal, 1);

    float wh0[8], wh1[8], hror[8];
    #pragma unroll
    for (int r = 0; r < 8; ++r) {
        wh0[r]  = W[gq0 * DTOT + IN_DIMC + jmap[r]];
        wh1[r]  = W[gq1 * DTOT + IN_DIMC + jmap[r]];
        hror[r] = h0[row * 8 + jmap[r]];
    }
    float c = c0[row * 8 + q];

    const bool ge1 = (q >= 1), ge2 = (q >= 2), ge4 = (q >= 4);
    const bool isT = (hB == 0);        // act1 = tanh for half 0, sigmoid half 1

    // 3-deep ZX prefetch (bias folded in gemm)
    float zb0  = ZX[(long)row * 32 + l16];
    float zb1  = ZX[(long)row * 32 + 16 + l16];
    float zn10 = ZX[((long)1 * BATCH_N + row) * 32 + l16];
    float zn11 = ZX[((long)1 * BATCH_N + row) * 32 + 16 + l16];
    float zn20 = ZX[((long)2 * BATCH_N + row) * 32 + l16];
    float zn21 = ZX[((long)2 * BATCH_N + row) * 32 + 16 + l16];

    float hlast = 0.f;
    for (int t = 0; t < SEQ_LEN; ++t) {
        const long tp = (t + 3 < SEQ_LEN) ? (t + 3) : (SEQ_LEN - 1);
        const float zn30 = ZX[(tp * BATCH_N + row) * 32 + l16];
        const float zn31 = ZX[(tp * BATCH_N + row) * 32 + 16 + l16];

        // z = zx+b+qp + Wh.h  (two 4-FMA chains each, summed)
        float s0a = fmaf(hror[0], wh0[0], zb0);
        s0a = fmaf(hror[1], wh0[1], s0a);
        s0a = fmaf(hror[2], wh0[2], s0a);
        s0a = fmaf(hror[3], wh0[3], s0a);
        float s0b = hror[4] * wh0[4];
        s0b = fmaf(hror[5], wh0[5], s0b);
        s0b = fmaf(hror[6], wh0[6], s0b);
        s0b = fmaf(hror[7], wh0[7], s0b);
        const float z0 = s0a + s0b;

        float s1a = fmaf(hror[0], wh1[0], zb1);
        s1a = fmaf(hror[1], wh1[1], s1a);
        s1a = fmaf(hror[2], wh1[2], s1a);
        s1a = fmaf(hror[3], wh1[3], s1a);
        float s1b = hror[4] * wh1[4];
        s1b = fmaf(hror[5], wh1[5], s1b);
        s1b = fmaf(hror[6], wh1[6], s1b);
        s1b = fmaf(hror[7], wh1[7], s1b);
        const float z1 = s1a + s1b;

        float p0 = __cosf(z0), p1 = __cosf(z1);

        // cumprod over q (single calibrated direction, wave-uniform branch)
        if (dirU) {
            { float v = DPP_F(p0, 0x111); p0 *= ge1 ? v : 1.f; }
            { float v = DPP_F(p1, 0x111); p1 *= ge1 ? v : 1.f; }
            { float v = DPP_F(p0, 0x112); p0 *= ge2 ? v : 1.f; }
            { float v = DPP_F(p1, 0x112); p1 *= ge2 ? v : 1.f; }
            { float v = DPP_F(p0, 0x114); p0 *= ge4 ? v : 1.f; }
            { float v = DPP_F(p1, 0x114); p1 *= ge4 ? v : 1.f; }
        } else {
            { float v = DPP_F(p0, 0x101); p0 *= ge1 ? v : 1.f; }
            { float v = DPP_F(p1, 0x101); p1 *= ge1 ? v : 1.f; }
            { float v = DPP_F(p0, 0x102); p0 *= ge2 ? v : 1.f; }
            { float v = DPP_F(p1, 0x102); p1 *= ge2 ? v : 1.f; }
            { float v = DPP_F(p0, 0x104); p0 *= ge4 ? v : 1.f; }
            { float v = DPP_F(p1, 0x104); p1 *= ge4 ? v : 1.f; }
        }

        // act0 = sigmoid(p0), poly (p0 in [-1,1] exactly)
        const float y0 = p0 * p0;
        const float P0 = fmaf(y0, fmaf(y0, SIG_A2, SIG_A1), SIG_A0);
        const float act0 = fmaf(p0, P0, 0.5f);

        // act1 = tanh(p1) [hB=0] or sigmoid(p1) [hB=1], both poly
        const float y1 = p1 * p1;
        const float P1s = fmaf(y1, fmaf(y1, SIG_A2, SIG_A1), SIG_A0);
        const float sg1 = fmaf(p1, P1s, 0.5f);
        const float P1t = fmaf(y1, fmaf(y1, fmaf(y1, TNH_T3, TNH_T2), TNH_T1), TNH_T0);
        const float th1 = p1 * P1t;
        const float act1 = isT ? th1 : sg1;

        // partner (l^8) exchange: row_ror:8 is self-inverse
        const float oth0 = DPP_F(act0, 0x128);
        const float oth1 = DPP_F(act1, 0x128);

        const float f_ = hB ? oth0 : act0;
        const float i_ = hB ? act0 : oth0;
        const float g_ = hB ? oth1 : act1;
        const float o_ = hB ? act1 : oth1;

        const float c2 = fmaf(f_, c, i_ * g_);
        // h2 = o * tanh(c2) = fma(r, 2o, -o), r = 1/(1+2^(c2*NL2E2))
        const float r_ = __builtin_amdgcn_rcpf(
            1.f + __builtin_amdgcn_exp2f(c2 * NL2E2));
        const float o2_ = o_ + o_;
        const float h2 = fmaf(r_, o2_, -o_);
        c = c2;
        hlast = h2;

        if (l16 < 8) out[((long)t * BATCH_N + row) * 8 + q] = h2;

        // h-broadcast for next step (matches jmap-calibrated weights)
        hror[0] = h2;
        hror[1] = DPP_F(h2, 0x121);
        hror[2] = DPP_F(h2, 0x122);
        hror[3] = DPP_F(h2, 0x123);
        hror[4] = DPP_F(h2, 0x124);
        hror[5] = DPP_F(h2, 0x125);
        hror[6] = DPP_F(h2, 0x126);
        hror[7] = DPP_F(h2, 0x127);

        zb0 = zn10; zb1 = zn11;
        zn10 = zn20; zn11 = zn21;
        zn20 = zn30; zn21 = zn31;
    }

    if (l16 < 8) {
        out[OUT_MAIN + row * 8 + q] = hlast;                  // h_f
        out[OUT_MAIN + BATCH_N * 8 + row * 8 + q] = c;        // c_f
    }
}

// ---------------------------------------------------------------------------
extern "C" void kernel_launch(void* const* d_in, const int* in_sizes, int n_in,
                              void* d_out, int out_size, void* d_ws, size_t ws_size,
                              hipStream_t stream)
{
    const float* X  = (const float*)d_in[0];
    const float* h0 = (const float*)d_in[1];
    const float* c0 = (const float*)d_in[2];
    const float* W  = (const float*)d_in[3];
    const float* bv = (const float*)d_in[4];
    const float* qp = (const float*)d_in[5];
    float* out = (float*)d_out;
    float* ZX  = (float*)d_ws;   // 262144 * 32 f32 = 32 MiB

    zx_gemm<<<(SEQ_LEN * BATCH_N) / 1024, 256, 0, stream>>>(X, W, bv, qp, ZX);
    qlstm_scan<<<BATCH_N / 4, 64, 0, stream>>>(ZX, W, h0, c0, out);
}